// Round 1
// baseline (1148.129 us; speedup 1.0000x reference)
//
#include <hip/hip_runtime.h>
#include <cstdint>

#define B_ 4
#define C_ 256
#define HW_ 4096
#define CPG_ 8
#define M_TOT 16384
#define SCALE 0.0625f

typedef __attribute__((ext_vector_type(4))) float f32x4;
typedef __attribute__((ext_vector_type(8))) unsigned short u16x8;
typedef __attribute__((ext_vector_type(4))) unsigned short u16x4;
typedef __attribute__((ext_vector_type(8))) __bf16 bf16x8;

static __device__ __forceinline__ unsigned short f2bf(float f) {
  unsigned int u = __builtin_bit_cast(unsigned int, f);
  u += 0x7fffu + ((u >> 16) & 1u);
  return (unsigned short)(u >> 16);
}
static __device__ __forceinline__ float bf2f(unsigned short s) {
  return __builtin_bit_cast(float, ((unsigned int)s) << 16);
}
static __device__ __forceinline__ bf16x8 ldbf8(const unsigned short* p) {
  return __builtin_bit_cast(bf16x8, *(const u16x8*)p);
}
// load 8 fp32 and convert to bf16x8 in-register (weights stay fp32 in HBM)
static __device__ __forceinline__ bf16x8 cvt8(const float* p) {
  f32x4 a = *(const f32x4*)p;
  f32x4 b = *(const f32x4*)(p + 4);
  u16x8 r;
  r[0] = f2bf(a[0]); r[1] = f2bf(a[1]); r[2] = f2bf(a[2]); r[3] = f2bf(a[3]);
  r[4] = f2bf(b[0]); r[5] = f2bf(b[1]); r[6] = f2bf(b[2]); r[7] = f2bf(b[3]);
  return __builtin_bit_cast(bf16x8, r);
}

// ---------------- GroupNorm -> t bf16 [b][s][c] ----------------
__global__ __launch_bounds__(256) void gn_kernel(const float* __restrict__ x,
    const float* __restrict__ gamma, const float* __restrict__ beta,
    unsigned short* __restrict__ t) {
  int bg = blockIdx.x;
  int b = bg >> 5, g = bg & 31;
  const float* xp = x + ((size_t)(b * C_ + g * CPG_)) * HW_;
  float s = 0.f, ss = 0.f;
  for (int i = threadIdx.x; i < CPG_ * HW_; i += 256) {
    float v = xp[i]; s += v; ss += v * v;
  }
#pragma unroll
  for (int m = 32; m; m >>= 1) { s += __shfl_xor(s, m); ss += __shfl_xor(ss, m); }
  __shared__ float red[8];
  if ((threadIdx.x & 63) == 0) { red[threadIdx.x >> 6] = s; red[4 + (threadIdx.x >> 6)] = ss; }
  __syncthreads();
  float S = red[0] + red[1] + red[2] + red[3];
  float SS = red[4] + red[5] + red[6] + red[7];
  float mean = S * (1.f / 32768.f);
  float var = SS * (1.f / 32768.f) - mean * mean;
  float rs = rsqrtf(var + 1e-6f);
  float gam[CPG_], bet[CPG_];
#pragma unroll
  for (int cc = 0; cc < CPG_; ++cc) {
    float gm = gamma[g * CPG_ + cc];
    gam[cc] = gm * rs;
    bet[cc] = beta[g * CPG_ + cc] - mean * gm * rs;
  }
  for (int sp = threadIdx.x; sp < HW_; sp += 256) {
    u16x8 o;
#pragma unroll
    for (int cc = 0; cc < CPG_; ++cc) {
      float v = xp[cc * HW_ + sp];
      o[cc] = f2bf(v * gam[cc] + bet[cc]);
    }
    *(u16x8*)(t + ((size_t)(b * HW_ + sp)) * C_ + g * CPG_) = o;
  }
}

// ---------------- u = sigmoid(t . wu + bu), one wave per token ----------------
__global__ __launch_bounds__(256) void u_kernel(const unsigned short* __restrict__ t,
    const float* __restrict__ wu, const float* __restrict__ bu,
    float* __restrict__ uout) {
  int w = threadIdx.x >> 6, l = threadIdx.x & 63;
  int tok = blockIdx.x * 4 + w;
  u16x4 tv = *(const u16x4*)(t + (size_t)tok * C_ + l * 4);
  f32x4 wv4 = *(const f32x4*)(wu + l * 4);
  float d = bf2f(tv[0]) * wv4[0] + bf2f(tv[1]) * wv4[1] +
            bf2f(tv[2]) * wv4[2] + bf2f(tv[3]) * wv4[3];
#pragma unroll
  for (int m = 32; m; m >>= 1) d += __shfl_xor(d, m);
  if (l == 0) uout[tok] = 1.f / (1.f + __expf(-(d + bu[0])));
}

// ---------------- fused QKV projection GEMM ----------------
__global__ __launch_bounds__(256, 2) void qkv_kernel(const unsigned short* __restrict__ t,
    const float* __restrict__ wq, const float* __restrict__ wk, const float* __restrict__ wv,
    const float* __restrict__ bq, const float* __restrict__ bk, const float* __restrict__ bv,
    unsigned short* __restrict__ q, unsigned short* __restrict__ k,
    unsigned short* __restrict__ vt) {
  int mblk = blockIdx.x, nblk = blockIdx.y;
  int wsel = nblk >> 2;
  int n0 = (nblk & 3) * 64;
  const float* W = wsel == 0 ? wq : (wsel == 1 ? wk : wv);
  const float* bias = wsel == 0 ? bq : (wsel == 1 ? bk : bv);
  int wid = threadIdx.x >> 6, l = threadIdx.x & 63;
  int lr = l & 15, lg = l >> 4;
  int row = mblk * 64 + wid * 16 + lr;
  f32x4 acc[4] = {};
  const unsigned short* ap = t + (size_t)row * C_ + lg * 8;
#pragma unroll
  for (int kc = 0; kc < 8; ++kc) {
    bf16x8 a = ldbf8(ap + kc * 32);
#pragma unroll
    for (int j = 0; j < 4; ++j) {
      bf16x8 bb = cvt8(W + (size_t)(n0 + j * 16 + lr) * C_ + kc * 32 + lg * 8);
      acc[j] = __builtin_amdgcn_mfma_f32_16x16x32_bf16(a, bb, acc[j], 0, 0, 0);
    }
  }
  if (wsel < 2) {
    unsigned short* dst = wsel ? k : q;
#pragma unroll
    for (int j = 0; j < 4; ++j) {
      int col = n0 + j * 16 + lr;
      float bv_ = bias[col];
#pragma unroll
      for (int r = 0; r < 4; ++r)
        dst[(size_t)(mblk * 64 + wid * 16 + lg * 4 + r) * C_ + col] = f2bf(acc[j][r] + bv_);
    }
  } else {
    __shared__ float lds[64][65];
#pragma unroll
    for (int j = 0; j < 4; ++j) {
      float bv_ = bias[n0 + j * 16 + lr];
#pragma unroll
      for (int r = 0; r < 4; ++r)
        lds[wid * 16 + lg * 4 + r][j * 16 + lr] = acc[j][r] + bv_;
    }
    __syncthreads();
    int bb_ = (mblk * 64) >> 12;
    int s0 = (mblk * 64) & 4095;
    int ss = threadIdx.x & 63, cc0 = threadIdx.x >> 6;
    for (int cc = cc0; cc < 64; cc += 4)
      vt[((size_t)(bb_ * C_ + n0 + cc)) * HW_ + s0 + ss] = f2bf(lds[ss][cc]);
  }
}

// ---------------- flash attention: 16 q-rows/wave, 32 keys/tile ----------------
__global__ __launch_bounds__(256, 2) void flash_kernel(const unsigned short* __restrict__ q,
    const unsigned short* __restrict__ k, const unsigned short* __restrict__ vt,
    const float* __restrict__ u, unsigned short* __restrict__ o) {
  int b = blockIdx.y;
  int wid = threadIdx.x >> 6, l = threadIdx.x & 63;
  int lr = l & 15, lg = l >> 4;
  int qrow0 = blockIdx.x * 64 + wid * 16;
  __shared__ unsigned short P[2][4][16][32];
  bf16x8 qf[8];
  const unsigned short* qp = q + ((size_t)b * HW_ + qrow0 + lr) * C_ + lg * 8;
#pragma unroll
  for (int kc = 0; kc < 8; ++kc) qf[kc] = ldbf8(qp + kc * 32);
  f32x4 oa[16];
#pragma unroll
  for (int nt = 0; nt < 16; ++nt) oa[nt] = (f32x4){0.f, 0.f, 0.f, 0.f};
  float mrow[4] = {-1e30f, -1e30f, -1e30f, -1e30f};
  float lrow[4] = {0.f, 0.f, 0.f, 0.f};
  const unsigned short* kb = k + (size_t)b * HW_ * C_;
  const unsigned short* vb = vt + (size_t)b * C_ * HW_;
  const float* ub = u + b * HW_;
  for (int kt = 0; kt < 128; ++kt) {
    int key0 = kt * 32;
    f32x4 s0 = {0.f, 0.f, 0.f, 0.f}, s1 = {0.f, 0.f, 0.f, 0.f};
    const unsigned short* kp = kb + (size_t)(key0 + lr) * C_ + lg * 8;
#pragma unroll
    for (int kc = 0; kc < 8; ++kc) {
      bf16x8 k0 = ldbf8(kp + kc * 32);
      bf16x8 k1 = ldbf8(kp + 16 * C_ + kc * 32);
      s0 = __builtin_amdgcn_mfma_f32_16x16x32_bf16(qf[kc], k0, s0, 0, 0, 0);
      s1 = __builtin_amdgcn_mfma_f32_16x16x32_bf16(qf[kc], k1, s1, 0, 0, 0);
    }
    float f0 = SCALE * ub[key0 + lr];
    float f1 = SCALE * ub[key0 + 16 + lr];
    float scr[4];
#pragma unroll
    for (int r = 0; r < 4; ++r) {
      float a0 = s0[r] * f0, a1 = s1[r] * f1;
      float mx = fmaxf(a0, a1);
#pragma unroll
      for (int mm = 1; mm < 16; mm <<= 1) mx = fmaxf(mx, __shfl_xor(mx, mm));
      float mnew = fmaxf(mrow[r], mx);
      float e0 = __expf(a0 - mnew), e1 = __expf(a1 - mnew);
      float sc = __expf(mrow[r] - mnew);
      float rsum = e0 + e1;
#pragma unroll
      for (int mm = 1; mm < 16; mm <<= 1) rsum += __shfl_xor(rsum, mm);
      lrow[r] = lrow[r] * sc + rsum;
      mrow[r] = mnew;
      scr[r] = sc;
      P[kt & 1][wid][lg * 4 + r][lr] = f2bf(e0);
      P[kt & 1][wid][lg * 4 + r][lr + 16] = f2bf(e1);
    }
#pragma unroll
    for (int nt = 0; nt < 16; ++nt) {
      oa[nt][0] *= scr[0]; oa[nt][1] *= scr[1];
      oa[nt][2] *= scr[2]; oa[nt][3] *= scr[3];
    }
    __syncthreads();
    bf16x8 pa = ldbf8(&P[kt & 1][wid][lr][lg * 8]);
    const unsigned short* vp = vb + (size_t)lr * HW_ + key0 + lg * 8;
#pragma unroll
    for (int nt = 0; nt < 16; ++nt) {
      bf16x8 vf = ldbf8(vp + (size_t)nt * 16 * HW_);
      oa[nt] = __builtin_amdgcn_mfma_f32_16x16x32_bf16(pa, vf, oa[nt], 0, 0, 0);
    }
  }
#pragma unroll
  for (int r = 0; r < 4; ++r) {
    float inv = 1.f / lrow[r];
    size_t orow = ((size_t)b * HW_ + qrow0 + lg * 4 + r) * C_;
#pragma unroll
    for (int nt = 0; nt < 16; ++nt)
      o[orow + nt * 16 + lr] = f2bf(oa[nt][r] * inv);
  }
}

// ---------------- out-proj + bias + residual, transposed fp32 write ----------------
__global__ __launch_bounds__(256, 2) void proj_kernel(const unsigned short* __restrict__ o,
    const float* __restrict__ wp, const float* __restrict__ bp,
    const float* __restrict__ x, float* __restrict__ y) {
  int mblk = blockIdx.x, nblk = blockIdx.y;
  int n0 = nblk * 64;
  int wid = threadIdx.x >> 6, l = threadIdx.x & 63;
  int lr = l & 15, lg = l >> 4;
  int row = mblk * 64 + wid * 16 + lr;
  f32x4 acc[4] = {};
  const unsigned short* ap = o + (size_t)row * C_ + lg * 8;
#pragma unroll
  for (int kc = 0; kc < 8; ++kc) {
    bf16x8 a = ldbf8(ap + kc * 32);
#pragma unroll
    for (int j = 0; j < 4; ++j) {
      bf16x8 bb = cvt8(wp + (size_t)(n0 + j * 16 + lr) * C_ + kc * 32 + lg * 8);
      acc[j] = __builtin_amdgcn_mfma_f32_16x16x32_bf16(a, bb, acc[j], 0, 0, 0);
    }
  }
  __shared__ float lds[64][65];
#pragma unroll
  for (int j = 0; j < 4; ++j) {
    float bv_ = bp[n0 + j * 16 + lr];
#pragma unroll
    for (int r = 0; r < 4; ++r)
      lds[wid * 16 + lg * 4 + r][j * 16 + lr] = acc[j][r] + bv_;
  }
  __syncthreads();
  int bb_ = (mblk * 64) >> 12;
  int s0 = (mblk * 64) & 4095;
  int ss = threadIdx.x & 63, cc0 = threadIdx.x >> 6;
  for (int cc = cc0; cc < 64; cc += 4) {
    size_t idx = ((size_t)(bb_ * C_ + n0 + cc)) * HW_ + s0 + ss;
    y[idx] = x[idx] + lds[ss][cc];
  }
}

extern "C" void kernel_launch(void* const* d_in, const int* in_sizes, int n_in,
                              void* d_out, int out_size, void* d_ws, size_t ws_size,
                              hipStream_t stream) {
  const float* x     = (const float*)d_in[0];
  const float* gamma = (const float*)d_in[1];
  const float* beta  = (const float*)d_in[2];
  const float* wq    = (const float*)d_in[3];
  const float* bq    = (const float*)d_in[4];
  const float* wk    = (const float*)d_in[5];
  const float* bk    = (const float*)d_in[6];
  const float* wv    = (const float*)d_in[7];
  const float* bv    = (const float*)d_in[8];
  const float* wu    = (const float*)d_in[9];
  const float* bu    = (const float*)d_in[10];
  const float* wp    = (const float*)d_in[11];
  const float* bp    = (const float*)d_in[12];

  float* y = (float*)d_out;
  float* uout = y + (size_t)B_ * C_ * HW_;  // output 1 region, also read by flash

  unsigned short* t  = (unsigned short*)d_ws;        // 8 MB, reused as attn output O
  unsigned short* q  = t + (size_t)M_TOT * C_;       // 8 MB
  unsigned short* kk = q + (size_t)M_TOT * C_;       // 8 MB
  unsigned short* vt = kk + (size_t)M_TOT * C_;      // 8 MB, [b][c][s]

  gn_kernel<<<128, 256, 0, stream>>>(x, gamma, beta, t);
  u_kernel<<<4096, 256, 0, stream>>>(t, wu, bu, uout);
  qkv_kernel<<<dim3(256, 12), 256, 0, stream>>>(t, wq, wk, wv, bq, bk, bv, q, kk, vt);
  flash_kernel<<<dim3(64, 4), 256, 0, stream>>>(q, kk, vt, uout, t);
  proj_kernel<<<dim3(256, 4), 256, 0, stream>>>(t, wp, bp, x, y);
}

// Round 2
// 722.062 us; speedup vs baseline: 1.5901x; 1.5901x over previous
//
#include <hip/hip_runtime.h>
#include <cstdint>

#define B_ 4
#define C_ 256
#define HW_ 4096
#define CPG_ 8
#define M_TOT 16384
#define SCALE 0.0625f

typedef __attribute__((ext_vector_type(4))) float f32x4;
typedef __attribute__((ext_vector_type(8))) unsigned short u16x8;
typedef __attribute__((ext_vector_type(4))) unsigned short u16x4;
typedef __attribute__((ext_vector_type(8))) __bf16 bf16x8;

static __device__ __forceinline__ unsigned short f2bf(float f) {
  unsigned int u = __builtin_bit_cast(unsigned int, f);
  u += 0x7fffu + ((u >> 16) & 1u);
  return (unsigned short)(u >> 16);
}
static __device__ __forceinline__ float bf2f(unsigned short s) {
  return __builtin_bit_cast(float, ((unsigned int)s) << 16);
}
static __device__ __forceinline__ bf16x8 ldbf8(const unsigned short* p) {
  return __builtin_bit_cast(bf16x8, *(const u16x8*)p);
}
// load 8 fp32 and convert to bf16x8 in-register (weights stay fp32 in HBM)
static __device__ __forceinline__ bf16x8 cvt8(const float* p) {
  f32x4 a = *(const f32x4*)p;
  f32x4 b = *(const f32x4*)(p + 4);
  u16x8 r;
  r[0] = f2bf(a[0]); r[1] = f2bf(a[1]); r[2] = f2bf(a[2]); r[3] = f2bf(a[3]);
  r[4] = f2bf(b[0]); r[5] = f2bf(b[1]); r[6] = f2bf(b[2]); r[7] = f2bf(b[3]);
  return __builtin_bit_cast(bf16x8, r);
}

// ---------------- GroupNorm -> t bf16 [b][s][c] ----------------
__global__ __launch_bounds__(256) void gn_kernel(const float* __restrict__ x,
    const float* __restrict__ gamma, const float* __restrict__ beta,
    unsigned short* __restrict__ t) {
  int bg = blockIdx.x;
  int b = bg >> 5, g = bg & 31;
  const float* xp = x + ((size_t)(b * C_ + g * CPG_)) * HW_;
  float s = 0.f, ss = 0.f;
  for (int i = threadIdx.x; i < CPG_ * HW_; i += 256) {
    float v = xp[i]; s += v; ss += v * v;
  }
#pragma unroll
  for (int m = 32; m; m >>= 1) { s += __shfl_xor(s, m); ss += __shfl_xor(ss, m); }
  __shared__ float red[8];
  if ((threadIdx.x & 63) == 0) { red[threadIdx.x >> 6] = s; red[4 + (threadIdx.x >> 6)] = ss; }
  __syncthreads();
  float S = red[0] + red[1] + red[2] + red[3];
  float SS = red[4] + red[5] + red[6] + red[7];
  float mean = S * (1.f / 32768.f);
  float var = SS * (1.f / 32768.f) - mean * mean;
  float rs = rsqrtf(var + 1e-6f);
  float gam[CPG_], bet[CPG_];
#pragma unroll
  for (int cc = 0; cc < CPG_; ++cc) {
    float gm = gamma[g * CPG_ + cc];
    gam[cc] = gm * rs;
    bet[cc] = beta[g * CPG_ + cc] - mean * gm * rs;
  }
  for (int sp = threadIdx.x; sp < HW_; sp += 256) {
    u16x8 o;
#pragma unroll
    for (int cc = 0; cc < CPG_; ++cc) {
      float v = xp[cc * HW_ + sp];
      o[cc] = f2bf(v * gam[cc] + bet[cc]);
    }
    *(u16x8*)(t + ((size_t)(b * HW_ + sp)) * C_ + g * CPG_) = o;
  }
}

// ---------------- u = sigmoid(t . wu + bu), one wave per token ----------------
__global__ __launch_bounds__(256) void u_kernel(const unsigned short* __restrict__ t,
    const float* __restrict__ wu, const float* __restrict__ bu,
    float* __restrict__ uout) {
  int w = threadIdx.x >> 6, l = threadIdx.x & 63;
  int tok = blockIdx.x * 4 + w;
  u16x4 tv = *(const u16x4*)(t + (size_t)tok * C_ + l * 4);
  f32x4 wv4 = *(const f32x4*)(wu + l * 4);
  float d = bf2f(tv[0]) * wv4[0] + bf2f(tv[1]) * wv4[1] +
            bf2f(tv[2]) * wv4[2] + bf2f(tv[3]) * wv4[3];
#pragma unroll
  for (int m = 32; m; m >>= 1) d += __shfl_xor(d, m);
  if (l == 0) uout[tok] = 1.f / (1.f + __expf(-(d + bu[0])));
}

// ---------------- fused QKV projection GEMM ----------------
__global__ __launch_bounds__(256, 2) void qkv_kernel(const unsigned short* __restrict__ t,
    const float* __restrict__ wq, const float* __restrict__ wk, const float* __restrict__ wv,
    const float* __restrict__ bq, const float* __restrict__ bk, const float* __restrict__ bv,
    unsigned short* __restrict__ q, unsigned short* __restrict__ k,
    unsigned short* __restrict__ vt) {
  int mblk = blockIdx.x, nblk = blockIdx.y;
  int wsel = nblk >> 2;
  int n0 = (nblk & 3) * 64;
  const float* W = wsel == 0 ? wq : (wsel == 1 ? wk : wv);
  const float* bias = wsel == 0 ? bq : (wsel == 1 ? bk : bv);
  int wid = threadIdx.x >> 6, l = threadIdx.x & 63;
  int lr = l & 15, lg = l >> 4;
  int row = mblk * 64 + wid * 16 + lr;
  f32x4 acc[4] = {};
  const unsigned short* ap = t + (size_t)row * C_ + lg * 8;
#pragma unroll
  for (int kc = 0; kc < 8; ++kc) {
    bf16x8 a = ldbf8(ap + kc * 32);
#pragma unroll
    for (int j = 0; j < 4; ++j) {
      bf16x8 bb = cvt8(W + (size_t)(n0 + j * 16 + lr) * C_ + kc * 32 + lg * 8);
      acc[j] = __builtin_amdgcn_mfma_f32_16x16x32_bf16(a, bb, acc[j], 0, 0, 0);
    }
  }
  if (wsel < 2) {
    unsigned short* dst = wsel ? k : q;
#pragma unroll
    for (int j = 0; j < 4; ++j) {
      int col = n0 + j * 16 + lr;
      float bv_ = bias[col];
#pragma unroll
      for (int r = 0; r < 4; ++r)
        dst[(size_t)(mblk * 64 + wid * 16 + lg * 4 + r) * C_ + col] = f2bf(acc[j][r] + bv_);
    }
  } else {
    __shared__ float lds[64][65];
#pragma unroll
    for (int j = 0; j < 4; ++j) {
      float bv_ = bias[n0 + j * 16 + lr];
#pragma unroll
      for (int r = 0; r < 4; ++r)
        lds[wid * 16 + lg * 4 + r][j * 16 + lr] = acc[j][r] + bv_;
    }
    __syncthreads();
    int bb_ = (mblk * 64) >> 12;
    int s0 = (mblk * 64) & 4095;
    int ss = threadIdx.x & 63, cc0 = threadIdx.x >> 6;
    for (int cc = cc0; cc < 64; cc += 4)
      vt[((size_t)(bb_ * C_ + n0 + cc)) * HW_ + s0 + ss] = f2bf(lds[ss][cc]);
  }
}

// ---------------- flash attention v2 ----------------
// One block per 16 q-rows; 4 waves split the 4096 keys into 1024-key quarters
// with private online-softmax state; end-of-block combine through LDS.
// No inner-loop barriers (P tile is per-wave private; same-wave LDS ops are
// in-order). 1024 blocks x 4 waves = 16 waves/CU target occupancy.
__global__ __launch_bounds__(256, 4) void flash_kernel(const unsigned short* __restrict__ q,
    const unsigned short* __restrict__ k, const unsigned short* __restrict__ vt,
    const float* __restrict__ u, unsigned short* __restrict__ o) {
  int tile = blockIdx.x;            // 0..1023
  int b = tile >> 8;
  int qrow0 = (tile & 255) * 16;    // within batch
  int wid = threadIdx.x >> 6, l = threadIdx.x & 63;
  int lr = l & 15, lg = l >> 4;

  __shared__ unsigned short P[4][16][32];   // per-wave private P tile
  __shared__ float Oacc[16][260];
  __shared__ float cmb_m[4][16], cmb_l[4][16];

  bf16x8 qf[8];
  const unsigned short* qp = q + ((size_t)b * HW_ + qrow0 + lr) * C_ + lg * 8;
#pragma unroll
  for (int kc = 0; kc < 8; ++kc) qf[kc] = ldbf8(qp + kc * 32);

  f32x4 oa[16];
#pragma unroll
  for (int nt = 0; nt < 16; ++nt) oa[nt] = (f32x4){0.f, 0.f, 0.f, 0.f};
  float mrow[4] = {-1e30f, -1e30f, -1e30f, -1e30f};
  float lrow[4] = {0.f, 0.f, 0.f, 0.f};

  const unsigned short* kb = k + (size_t)b * HW_ * C_;
  const unsigned short* vb = vt + (size_t)b * C_ * HW_;
  const float* ub = u + b * HW_;

  for (int kt = 0; kt < 32; ++kt) {
    int key0 = (wid * 32 + kt) * 32;   // this wave's 1024-key quarter
    f32x4 s0 = {0.f, 0.f, 0.f, 0.f}, s1 = {0.f, 0.f, 0.f, 0.f};
    const unsigned short* kp = kb + (size_t)(key0 + lr) * C_ + lg * 8;
#pragma unroll
    for (int kc = 0; kc < 8; ++kc) {
      bf16x8 k0 = ldbf8(kp + kc * 32);
      bf16x8 k1 = ldbf8(kp + 16 * C_ + kc * 32);
      s0 = __builtin_amdgcn_mfma_f32_16x16x32_bf16(qf[kc], k0, s0, 0, 0, 0);
      s1 = __builtin_amdgcn_mfma_f32_16x16x32_bf16(qf[kc], k1, s1, 0, 0, 0);
    }
    float f0 = SCALE * ub[key0 + lr];
    float f1 = SCALE * ub[key0 + 16 + lr];
    float scr[4];
#pragma unroll
    for (int r = 0; r < 4; ++r) {
      float a0 = s0[r] * f0, a1 = s1[r] * f1;
      float mx = fmaxf(a0, a1);
#pragma unroll
      for (int mm = 1; mm < 16; mm <<= 1) mx = fmaxf(mx, __shfl_xor(mx, mm));
      float mnew = fmaxf(mrow[r], mx);
      float e0 = __expf(a0 - mnew), e1 = __expf(a1 - mnew);
      float sc = __expf(mrow[r] - mnew);
      float rsum = e0 + e1;
#pragma unroll
      for (int mm = 1; mm < 16; mm <<= 1) rsum += __shfl_xor(rsum, mm);
      lrow[r] = lrow[r] * sc + rsum;
      mrow[r] = mnew;
      scr[r] = sc;
      P[wid][lg * 4 + r][lr] = f2bf(e0);
      P[wid][lg * 4 + r][lr + 16] = f2bf(e1);
    }
#pragma unroll
    for (int nt = 0; nt < 16; ++nt) {
      oa[nt][0] *= scr[0]; oa[nt][1] *= scr[1];
      oa[nt][2] *= scr[2]; oa[nt][3] *= scr[3];
    }
    bf16x8 pa = ldbf8(&P[wid][lr][lg * 8]);
    const unsigned short* vp = vb + (size_t)lr * HW_ + key0 + lg * 8;
#pragma unroll
    for (int nt = 0; nt < 16; ++nt) {
      bf16x8 vf = ldbf8(vp + (size_t)nt * 16 * HW_);
      oa[nt] = __builtin_amdgcn_mfma_f32_16x16x32_bf16(pa, vf, oa[nt], 0, 0, 0);
    }
  }

  // ---- cross-wave combine ----
#pragma unroll
  for (int r = 0; r < 4; ++r)
    if (lr == 0) { cmb_m[wid][lg * 4 + r] = mrow[r]; cmb_l[wid][lg * 4 + r] = lrow[r]; }
  __syncthreads();
  float scl[4];
#pragma unroll
  for (int r = 0; r < 4; ++r) {
    int row = lg * 4 + r;
    float M = fmaxf(fmaxf(cmb_m[0][row], cmb_m[1][row]),
                    fmaxf(cmb_m[2][row], cmb_m[3][row]));
    scl[r] = __expf(mrow[r] - M);
  }
  for (int w = 0; w < 4; ++w) {
    if (wid == w) {
#pragma unroll
      for (int nt = 0; nt < 16; ++nt)
#pragma unroll
        for (int r = 0; r < 4; ++r) {
          float v = oa[nt][r] * scl[r];
          if (w == 0) Oacc[lg * 4 + r][nt * 16 + lr] = v;
          else        Oacc[lg * 4 + r][nt * 16 + lr] += v;
        }
    }
    __syncthreads();
  }
  // final normalize + write, one full row (512B) per iteration, coalesced
  for (int r = 0; r < 16; ++r) {
    float M = fmaxf(fmaxf(cmb_m[0][r], cmb_m[1][r]),
                    fmaxf(cmb_m[2][r], cmb_m[3][r]));
    float L = cmb_l[0][r] * __expf(cmb_m[0][r] - M) +
              cmb_l[1][r] * __expf(cmb_m[1][r] - M) +
              cmb_l[2][r] * __expf(cmb_m[2][r] - M) +
              cmb_l[3][r] * __expf(cmb_m[3][r] - M);
    o[((size_t)b * HW_ + qrow0 + r) * C_ + threadIdx.x] =
        f2bf(Oacc[r][threadIdx.x] * (1.f / L));
  }
}

// ---------------- out-proj + bias + residual, transposed fp32 write ----------------
__global__ __launch_bounds__(256, 2) void proj_kernel(const unsigned short* __restrict__ o,
    const float* __restrict__ wp, const float* __restrict__ bp,
    const float* __restrict__ x, float* __restrict__ y) {
  int mblk = blockIdx.x, nblk = blockIdx.y;
  int n0 = nblk * 64;
  int wid = threadIdx.x >> 6, l = threadIdx.x & 63;
  int lr = l & 15, lg = l >> 4;
  int row = mblk * 64 + wid * 16 + lr;
  f32x4 acc[4] = {};
  const unsigned short* ap = o + (size_t)row * C_ + lg * 8;
#pragma unroll
  for (int kc = 0; kc < 8; ++kc) {
    bf16x8 a = ldbf8(ap + kc * 32);
#pragma unroll
    for (int j = 0; j < 4; ++j) {
      bf16x8 bb = cvt8(wp + (size_t)(n0 + j * 16 + lr) * C_ + kc * 32 + lg * 8);
      acc[j] = __builtin_amdgcn_mfma_f32_16x16x32_bf16(a, bb, acc[j], 0, 0, 0);
    }
  }
  __shared__ float lds[64][65];
#pragma unroll
  for (int j = 0; j < 4; ++j) {
    float bv_ = bp[n0 + j * 16 + lr];
#pragma unroll
    for (int r = 0; r < 4; ++r)
      lds[wid * 16 + lg * 4 + r][j * 16 + lr] = acc[j][r] + bv_;
  }
  __syncthreads();
  int bb_ = (mblk * 64) >> 12;
  int s0 = (mblk * 64) & 4095;
  int ss = threadIdx.x & 63, cc0 = threadIdx.x >> 6;
  for (int cc = cc0; cc < 64; cc += 4) {
    size_t idx = ((size_t)(bb_ * C_ + n0 + cc)) * HW_ + s0 + ss;
    y[idx] = x[idx] + lds[ss][cc];
  }
}

extern "C" void kernel_launch(void* const* d_in, const int* in_sizes, int n_in,
                              void* d_out, int out_size, void* d_ws, size_t ws_size,
                              hipStream_t stream) {
  const float* x     = (const float*)d_in[0];
  const float* gamma = (const float*)d_in[1];
  const float* beta  = (const float*)d_in[2];
  const float* wq    = (const float*)d_in[3];
  const float* bq    = (const float*)d_in[4];
  const float* wk    = (const float*)d_in[5];
  const float* bk    = (const float*)d_in[6];
  const float* wv    = (const float*)d_in[7];
  const float* bv    = (const float*)d_in[8];
  const float* wu    = (const float*)d_in[9];
  const float* bu    = (const float*)d_in[10];
  const float* wp    = (const float*)d_in[11];
  const float* bp    = (const float*)d_in[12];

  float* y = (float*)d_out;
  float* uout = y + (size_t)B_ * C_ * HW_;  // output 1 region, also read by flash

  unsigned short* t  = (unsigned short*)d_ws;        // 8 MB, reused as attn output O
  unsigned short* q  = t + (size_t)M_TOT * C_;       // 8 MB
  unsigned short* kk = q + (size_t)M_TOT * C_;       // 8 MB
  unsigned short* vt = kk + (size_t)M_TOT * C_;      // 8 MB, [b][c][s]

  gn_kernel<<<128, 256, 0, stream>>>(x, gamma, beta, t);
  u_kernel<<<4096, 256, 0, stream>>>(t, wu, bu, uout);
  qkv_kernel<<<dim3(256, 12), 256, 0, stream>>>(t, wq, wk, wv, bq, bk, bv, q, kk, vt);
  flash_kernel<<<1024, 256, 0, stream>>>(q, kk, vt, uout, t);
  proj_kernel<<<dim3(256, 4), 256, 0, stream>>>(t, wp, bp, x, y);
}

// Round 3
// 353.589 us; speedup vs baseline: 3.2471x; 2.0421x over previous
//
#include <hip/hip_runtime.h>
#include <cstdint>

#define B_ 4
#define C_ 256
#define HW_ 4096
#define CPG_ 8
#define M_TOT 16384
#define SCALE 0.0625f
#define FLASH_LDS 140800

typedef __attribute__((ext_vector_type(4))) float f32x4;
typedef __attribute__((ext_vector_type(8))) unsigned short u16x8;
typedef __attribute__((ext_vector_type(4))) unsigned short u16x4;
typedef __attribute__((ext_vector_type(8))) __bf16 bf16x8;

static __device__ __forceinline__ unsigned short f2bf(float f) {
  unsigned int u = __builtin_bit_cast(unsigned int, f);
  u += 0x7fffu + ((u >> 16) & 1u);
  return (unsigned short)(u >> 16);
}
static __device__ __forceinline__ float bf2f(unsigned short s) {
  return __builtin_bit_cast(float, ((unsigned int)s) << 16);
}
static __device__ __forceinline__ bf16x8 ldbf8(const unsigned short* p) {
  return __builtin_bit_cast(bf16x8, *(const u16x8*)p);
}
static __device__ __forceinline__ bf16x8 cvt8(const float* p) {
  f32x4 a = *(const f32x4*)p;
  f32x4 b = *(const f32x4*)(p + 4);
  u16x8 r;
  r[0] = f2bf(a[0]); r[1] = f2bf(a[1]); r[2] = f2bf(a[2]); r[3] = f2bf(a[3]);
  r[4] = f2bf(b[0]); r[5] = f2bf(b[1]); r[6] = f2bf(b[2]); r[7] = f2bf(b[3]);
  return __builtin_bit_cast(bf16x8, r);
}
// async global->LDS, 16B per lane; LDS dest must be wave-uniform base
static __device__ __forceinline__ void gload16(const void* g, void* l) {
  __builtin_amdgcn_global_load_lds(
      (const __attribute__((address_space(1))) unsigned int*)g,
      (__attribute__((address_space(3))) unsigned int*)l, 16, 0, 0);
}

// ---------------- GroupNorm -> t bf16 [b][s][c] ----------------
__global__ __launch_bounds__(256) void gn_kernel(const float* __restrict__ x,
    const float* __restrict__ gamma, const float* __restrict__ beta,
    unsigned short* __restrict__ t) {
  int bg = blockIdx.x;
  int b = bg >> 5, g = bg & 31;
  const float* xp = x + ((size_t)(b * C_ + g * CPG_)) * HW_;
  float s = 0.f, ss = 0.f;
  for (int i = threadIdx.x; i < CPG_ * HW_; i += 256) {
    float v = xp[i]; s += v; ss += v * v;
  }
#pragma unroll
  for (int m = 32; m; m >>= 1) { s += __shfl_xor(s, m); ss += __shfl_xor(ss, m); }
  __shared__ float red[8];
  if ((threadIdx.x & 63) == 0) { red[threadIdx.x >> 6] = s; red[4 + (threadIdx.x >> 6)] = ss; }
  __syncthreads();
  float S = red[0] + red[1] + red[2] + red[3];
  float SS = red[4] + red[5] + red[6] + red[7];
  float mean = S * (1.f / 32768.f);
  float var = SS * (1.f / 32768.f) - mean * mean;
  float rs = rsqrtf(var + 1e-6f);
  float gam[CPG_], bet[CPG_];
#pragma unroll
  for (int cc = 0; cc < CPG_; ++cc) {
    float gm = gamma[g * CPG_ + cc];
    gam[cc] = gm * rs;
    bet[cc] = beta[g * CPG_ + cc] - mean * gm * rs;
  }
  for (int sp = threadIdx.x; sp < HW_; sp += 256) {
    u16x8 o;
#pragma unroll
    for (int cc = 0; cc < CPG_; ++cc) {
      float v = xp[cc * HW_ + sp];
      o[cc] = f2bf(v * gam[cc] + bet[cc]);
    }
    *(u16x8*)(t + ((size_t)(b * HW_ + sp)) * C_ + g * CPG_) = o;
  }
}

// ---------------- u = sigmoid(t . wu + bu), one wave per token ----------------
__global__ __launch_bounds__(256) void u_kernel(const unsigned short* __restrict__ t,
    const float* __restrict__ wu, const float* __restrict__ bu,
    float* __restrict__ uout) {
  int w = threadIdx.x >> 6, l = threadIdx.x & 63;
  int tok = blockIdx.x * 4 + w;
  u16x4 tv = *(const u16x4*)(t + (size_t)tok * C_ + l * 4);
  f32x4 wv4 = *(const f32x4*)(wu + l * 4);
  float d = bf2f(tv[0]) * wv4[0] + bf2f(tv[1]) * wv4[1] +
            bf2f(tv[2]) * wv4[2] + bf2f(tv[3]) * wv4[3];
#pragma unroll
  for (int m = 32; m; m >>= 1) d += __shfl_xor(d, m);
  if (l == 0) uout[tok] = 1.f / (1.f + __expf(-(d + bu[0])));
}

// ---------------- fused QKV projection GEMM ----------------
__global__ __launch_bounds__(256, 2) void qkv_kernel(const unsigned short* __restrict__ t,
    const float* __restrict__ wq, const float* __restrict__ wk, const float* __restrict__ wv,
    const float* __restrict__ bq, const float* __restrict__ bk, const float* __restrict__ bv,
    unsigned short* __restrict__ q, unsigned short* __restrict__ k,
    unsigned short* __restrict__ vt) {
  int mblk = blockIdx.x, nblk = blockIdx.y;
  int wsel = nblk >> 2;
  int n0 = (nblk & 3) * 64;
  const float* W = wsel == 0 ? wq : (wsel == 1 ? wk : wv);
  const float* bias = wsel == 0 ? bq : (wsel == 1 ? bk : bv);
  int wid = threadIdx.x >> 6, l = threadIdx.x & 63;
  int lr = l & 15, lg = l >> 4;
  int row = mblk * 64 + wid * 16 + lr;
  f32x4 acc[4] = {};
  const unsigned short* ap = t + (size_t)row * C_ + lg * 8;
#pragma unroll
  for (int kc = 0; kc < 8; ++kc) {
    bf16x8 a = ldbf8(ap + kc * 32);
#pragma unroll
    for (int j = 0; j < 4; ++j) {
      bf16x8 bb = cvt8(W + (size_t)(n0 + j * 16 + lr) * C_ + kc * 32 + lg * 8);
      acc[j] = __builtin_amdgcn_mfma_f32_16x16x32_bf16(a, bb, acc[j], 0, 0, 0);
    }
  }
  if (wsel < 2) {
    unsigned short* dst = wsel ? k : q;
#pragma unroll
    for (int j = 0; j < 4; ++j) {
      int col = n0 + j * 16 + lr;
      float bv_ = bias[col];
#pragma unroll
      for (int r = 0; r < 4; ++r)
        dst[(size_t)(mblk * 64 + wid * 16 + lg * 4 + r) * C_ + col] = f2bf(acc[j][r] + bv_);
    }
  } else {
    __shared__ float lds[64][65];
#pragma unroll
    for (int j = 0; j < 4; ++j) {
      float bv_ = bias[n0 + j * 16 + lr];
#pragma unroll
      for (int r = 0; r < 4; ++r)
        lds[wid * 16 + lg * 4 + r][j * 16 + lr] = acc[j][r] + bv_;
    }
    __syncthreads();
    int bb_ = (mblk * 64) >> 12;
    int s0 = (mblk * 64) & 4095;
    int ss = threadIdx.x & 63, cc0 = threadIdx.x >> 6;
    for (int cc = cc0; cc < 64; cc += 4)
      vt[((size_t)(bb_ * C_ + n0 + cc)) * HW_ + s0 + ss] = f2bf(lds[ss][cc]);
  }
}

// ---------------- flash attention v3: LDS-staged, double-buffered ----------------
// 256 blocks x 512 threads (8 waves). Block = 64 q-rows. Waves 0-3: keys
// [0,2048) (q-subtiles 0-3); waves 4-7: keys [2048,4096). K/V tiles (32 keys)
// staged via global_load_lds into dynamic LDS, double-buffered. K tile uses
// both-sides XOR swizzle (byte ^= (row&7)<<4) to even LDS banks; V tile rows
// are 64B so linear layout is already bank-even. In-block pairwise combine.
__global__ __launch_bounds__(512, 2) void flash_kernel(const unsigned short* __restrict__ q,
    const unsigned short* __restrict__ k, const unsigned short* __restrict__ vt,
    const float* __restrict__ u, unsigned short* __restrict__ o) {
  extern __shared__ char smem[];
  // layout: Ks [2 buf][2 half][32*256 bf16]  @ 0      (65536 B)
  //         Vs [2 buf][2 half][256*32 bf16]  @ 65536  (65536 B)
  //         Pl [8 wave][16*32 bf16]          @ 131072 (8192 B)
  //         cmb_m [8][16] f32                @ 139264
  //         cmb_l [8][16] f32                @ 139776
  //         Lx [64] f32                      @ 140288
  // epilogue overlay: Oacc [64][260] f32     @ 0
  unsigned short* Pl = (unsigned short*)(smem + 131072);
  float* cmb_m = (float*)(smem + 139264);
  float* cmb_l = (float*)(smem + 139776);
  float* Lx    = (float*)(smem + 140288);
  float* Oacc  = (float*)smem;

  int blk = blockIdx.x;
  int b = blk >> 6;
  int qrow0 = (blk & 63) * 64;
  int tid = threadIdx.x;
  int wid = tid >> 6, l = tid & 63;
  int lr = l & 15, lg = l >> 4;
  int half = wid >> 2, qw = wid & 3;

  const unsigned short* kb = k + (size_t)b * HW_ * C_;
  const unsigned short* vb = vt + (size_t)b * C_ * HW_;
  const float* ub = u + b * HW_;

  bf16x8 qf[8];
  const unsigned short* qp = q + ((size_t)b * HW_ + qrow0 + qw * 16 + lr) * C_ + lg * 8;
#pragma unroll
  for (int kc = 0; kc < 8; ++kc) qf[kc] = ldbf8(qp + kc * 32);

  f32x4 oa[16];
#pragma unroll
  for (int nt = 0; nt < 16; ++nt) oa[nt] = (f32x4){0.f, 0.f, 0.f, 0.f};
  float mrow[4] = {-1e30f, -1e30f, -1e30f, -1e30f};
  float lrow[4] = {0.f, 0.f, 0.f, 0.f};

  // staging role: waves 0-3 stage K, waves 4-7 stage V; sh = half staged
  int sh = (wid >> 1) & 1;
  int tb = (wid & 1) * 8;

#define STAGE(IT, BUFN)                                                            \
  {                                                                                \
    int key0n = sh * 2048 + (IT) * 32;                                             \
    if (wid < 4) {                                                                 \
      _Pragma("unroll")                                                            \
      for (int j = 0; j < 8; ++j) {                                                \
        int t16 = tb + j;                                                          \
        int row = (t16 * 1024 + l * 16) >> 9;                                      \
        int cb = (l & 31) * 16;                                                    \
        const unsigned short* g =                                                  \
            kb + (size_t)(key0n + row) * C_ + ((cb ^ ((row & 7) << 4)) >> 1);      \
        gload16(g, smem + (BUFN) * 32768 + sh * 16384 + t16 * 1024);               \
      }                                                                            \
    } else {                                                                       \
      _Pragma("unroll")                                                            \
      for (int j = 0; j < 8; ++j) {                                                \
        int t16 = tb + j;                                                          \
        int ch = t16 * 16 + (l >> 2);                                              \
        const unsigned short* g = vb + (size_t)ch * HW_ + key0n + (l & 3) * 8;     \
        gload16(g, smem + 65536 + (BUFN) * 32768 + sh * 16384 + t16 * 1024);       \
      }                                                                            \
    }                                                                              \
  }

  STAGE(0, 0);
  __syncthreads();

  for (int it = 0; it < 64; ++it) {
    int buf = it & 1;
    if (it + 1 < 64) STAGE(it + 1, buf ^ 1);
    int key0 = half * 2048 + it * 32;
    float f0 = SCALE * ub[key0 + lr];
    float f1 = SCALE * ub[key0 + 16 + lr];
    const char* KB = smem + buf * 32768 + half * 16384;
    f32x4 s0 = {0.f, 0.f, 0.f, 0.f}, s1 = {0.f, 0.f, 0.f, 0.f};
#pragma unroll
    for (int kc = 0; kc < 8; ++kc) {
      int c = lg * 16 + kc * 64;
      int cs = c ^ ((lr & 7) << 4);
      bf16x8 k0 = ldbf8((const unsigned short*)(KB + lr * 512 + cs));
      bf16x8 k1 = ldbf8((const unsigned short*)(KB + (lr + 16) * 512 + cs));
      s0 = __builtin_amdgcn_mfma_f32_16x16x32_bf16(qf[kc], k0, s0, 0, 0, 0);
      s1 = __builtin_amdgcn_mfma_f32_16x16x32_bf16(qf[kc], k1, s1, 0, 0, 0);
    }
    float scr[4];
#pragma unroll
    for (int r = 0; r < 4; ++r) {
      float a0 = s0[r] * f0, a1 = s1[r] * f1;
      float mx = fmaxf(a0, a1);
#pragma unroll
      for (int mm = 1; mm < 16; mm <<= 1) mx = fmaxf(mx, __shfl_xor(mx, mm));
      float mnew = fmaxf(mrow[r], mx);
      float e0 = __expf(a0 - mnew), e1 = __expf(a1 - mnew);
      float sc = __expf(mrow[r] - mnew);
      float rsum = e0 + e1;
#pragma unroll
      for (int mm = 1; mm < 16; mm <<= 1) rsum += __shfl_xor(rsum, mm);
      lrow[r] = lrow[r] * sc + rsum;
      mrow[r] = mnew;
      scr[r] = sc;
      Pl[wid * 512 + (lg * 4 + r) * 32 + lr] = f2bf(e0);
      Pl[wid * 512 + (lg * 4 + r) * 32 + lr + 16] = f2bf(e1);
    }
#pragma unroll
    for (int nt = 0; nt < 16; ++nt) {
      oa[nt][0] *= scr[0]; oa[nt][1] *= scr[1];
      oa[nt][2] *= scr[2]; oa[nt][3] *= scr[3];
    }
    bf16x8 pa = ldbf8(Pl + wid * 512 + lr * 32 + lg * 8);
    const char* VB = smem + 65536 + buf * 32768 + half * 16384;
#pragma unroll
    for (int nt = 0; nt < 16; ++nt) {
      bf16x8 vf = ldbf8((const unsigned short*)(VB + (nt * 16 + lr) * 64 + lg * 16));
      oa[nt] = __builtin_amdgcn_mfma_f32_16x16x32_bf16(pa, vf, oa[nt], 0, 0, 0);
    }
    __syncthreads();
  }

  // ---- pairwise combine (wave qw <-> wave qw+4) ----
#pragma unroll
  for (int r = 0; r < 4; ++r)
    if (lr == 0) { cmb_m[wid * 16 + lg * 4 + r] = mrow[r]; cmb_l[wid * 16 + lg * 4 + r] = lrow[r]; }
  __syncthreads();
  float scl[4];
#pragma unroll
  for (int r = 0; r < 4; ++r) {
    float mo = cmb_m[(wid ^ 4) * 16 + lg * 4 + r];
    float M = fmaxf(mrow[r], mo);
    scl[r] = __expf(mrow[r] - M);
  }
  if (half == 0) {
#pragma unroll
    for (int nt = 0; nt < 16; ++nt)
#pragma unroll
      for (int r = 0; r < 4; ++r)
        Oacc[(qw * 16 + lg * 4 + r) * 260 + nt * 16 + lr] = oa[nt][r] * scl[r];
  }
  if (tid < 64) {
    float m0 = cmb_m[(tid >> 4) * 16 + (tid & 15)];
    float m1 = cmb_m[((tid >> 4) + 4) * 16 + (tid & 15)];
    float l0 = cmb_l[(tid >> 4) * 16 + (tid & 15)];
    float l1 = cmb_l[((tid >> 4) + 4) * 16 + (tid & 15)];
    float M = fmaxf(m0, m1);
    Lx[tid] = l0 * __expf(m0 - M) + l1 * __expf(m1 - M);
  }
  __syncthreads();
  if (half == 1) {
#pragma unroll
    for (int nt = 0; nt < 16; ++nt)
#pragma unroll
      for (int r = 0; r < 4; ++r)
        Oacc[(qw * 16 + lg * 4 + r) * 260 + nt * 16 + lr] += oa[nt][r] * scl[r];
  }
  __syncthreads();
  for (int e = tid; e < 64 * 256; e += 512) {
    int row = e >> 8, col = e & 255;
    o[((size_t)b * HW_ + qrow0 + row) * C_ + col] =
        f2bf(Oacc[row * 260 + col] * (1.f / Lx[row]));
  }
#undef STAGE
}

// ---------------- out-proj + bias + residual, transposed fp32 write ----------------
__global__ __launch_bounds__(256, 2) void proj_kernel(const unsigned short* __restrict__ o,
    const float* __restrict__ wp, const float* __restrict__ bp,
    const float* __restrict__ x, float* __restrict__ y) {
  int mblk = blockIdx.x, nblk = blockIdx.y;
  int n0 = nblk * 64;
  int wid = threadIdx.x >> 6, l = threadIdx.x & 63;
  int lr = l & 15, lg = l >> 4;
  int row = mblk * 64 + wid * 16 + lr;
  f32x4 acc[4] = {};
  const unsigned short* ap = o + (size_t)row * C_ + lg * 8;
#pragma unroll
  for (int kc = 0; kc < 8; ++kc) {
    bf16x8 a = ldbf8(ap + kc * 32);
#pragma unroll
    for (int j = 0; j < 4; ++j) {
      bf16x8 bb = cvt8(wp + (size_t)(n0 + j * 16 + lr) * C_ + kc * 32 + lg * 8);
      acc[j] = __builtin_amdgcn_mfma_f32_16x16x32_bf16(a, bb, acc[j], 0, 0, 0);
    }
  }
  __shared__ float lds[64][65];
#pragma unroll
  for (int j = 0; j < 4; ++j) {
    float bv_ = bp[n0 + j * 16 + lr];
#pragma unroll
    for (int r = 0; r < 4; ++r)
      lds[wid * 16 + lg * 4 + r][j * 16 + lr] = acc[j][r] + bv_;
  }
  __syncthreads();
  int bb_ = (mblk * 64) >> 12;
  int s0 = (mblk * 64) & 4095;
  int ss = threadIdx.x & 63, cc0 = threadIdx.x >> 6;
  for (int cc = cc0; cc < 64; cc += 4) {
    size_t idx = ((size_t)(bb_ * C_ + n0 + cc)) * HW_ + s0 + ss;
    y[idx] = x[idx] + lds[ss][cc];
  }
}

extern "C" void kernel_launch(void* const* d_in, const int* in_sizes, int n_in,
                              void* d_out, int out_size, void* d_ws, size_t ws_size,
                              hipStream_t stream) {
  const float* x     = (const float*)d_in[0];
  const float* gamma = (const float*)d_in[1];
  const float* beta  = (const float*)d_in[2];
  const float* wq    = (const float*)d_in[3];
  const float* bq    = (const float*)d_in[4];
  const float* wk    = (const float*)d_in[5];
  const float* bk    = (const float*)d_in[6];
  const float* wv    = (const float*)d_in[7];
  const float* bv    = (const float*)d_in[8];
  const float* wu    = (const float*)d_in[9];
  const float* bu    = (const float*)d_in[10];
  const float* wp    = (const float*)d_in[11];
  const float* bp    = (const float*)d_in[12];

  float* y = (float*)d_out;
  float* uout = y + (size_t)B_ * C_ * HW_;  // output 1 region, also read by flash

  unsigned short* t  = (unsigned short*)d_ws;        // 8 MB, reused as attn output O
  unsigned short* q  = t + (size_t)M_TOT * C_;       // 8 MB
  unsigned short* kk = q + (size_t)M_TOT * C_;       // 8 MB
  unsigned short* vt = kk + (size_t)M_TOT * C_;      // 8 MB, [b][c][s]

  hipFuncSetAttribute((const void*)flash_kernel,
                      hipFuncAttributeMaxDynamicSharedMemorySize, FLASH_LDS);

  gn_kernel<<<128, 256, 0, stream>>>(x, gamma, beta, t);
  u_kernel<<<4096, 256, 0, stream>>>(t, wu, bu, uout);
  qkv_kernel<<<dim3(256, 12), 256, 0, stream>>>(t, wq, wk, wv, bq, bk, bv, q, kk, vt);
  flash_kernel<<<256, 512, FLASH_LDS, stream>>>(q, kk, vt, uout, t);
  proj_kernel<<<dim3(256, 4), 256, 0, stream>>>(t, wp, bp, x, y);
}

// Round 4
// 241.682 us; speedup vs baseline: 4.7506x; 1.4630x over previous
//
#include <hip/hip_runtime.h>
#include <cstdint>

#define B_ 4
#define C_ 256
#define HW_ 4096
#define CPG_ 8
#define M_TOT 16384
#define SCALE 0.0625f
#define FLASH_LDS 142592

typedef __attribute__((ext_vector_type(4))) float f32x4;
typedef __attribute__((ext_vector_type(8))) unsigned short u16x8;
typedef __attribute__((ext_vector_type(4))) unsigned short u16x4;
typedef __attribute__((ext_vector_type(8))) __bf16 bf16x8;

static __device__ __forceinline__ unsigned short f2bf(float f) {
  unsigned int u = __builtin_bit_cast(unsigned int, f);
  u += 0x7fffu + ((u >> 16) & 1u);
  return (unsigned short)(u >> 16);
}
static __device__ __forceinline__ float bf2f(unsigned short s) {
  return __builtin_bit_cast(float, ((unsigned int)s) << 16);
}
static __device__ __forceinline__ bf16x8 ldbf8(const unsigned short* p) {
  return __builtin_bit_cast(bf16x8, *(const u16x8*)p);
}
static __device__ __forceinline__ bf16x8 cvt8(const float* p) {
  f32x4 a = *(const f32x4*)p;
  f32x4 b = *(const f32x4*)(p + 4);
  u16x8 r;
  r[0] = f2bf(a[0]); r[1] = f2bf(a[1]); r[2] = f2bf(a[2]); r[3] = f2bf(a[3]);
  r[4] = f2bf(b[0]); r[5] = f2bf(b[1]); r[6] = f2bf(b[2]); r[7] = f2bf(b[3]);
  return __builtin_bit_cast(bf16x8, r);
}
// async global->LDS, 16B per lane; LDS dest must be wave-uniform base
static __device__ __forceinline__ void gload16(const void* g, void* l) {
  __builtin_amdgcn_global_load_lds(
      (const __attribute__((address_space(1))) unsigned int*)g,
      (__attribute__((address_space(3))) unsigned int*)l, 16, 0, 0);
}
// DPP butterfly steps within 16-lane groups (VALU pipe, not LDS):
// xor1 = quad_perm[1,0,3,2]=0xB1, xor2 = quad_perm[2,3,0,1]=0x4E,
// level3 = row_half_mirror (lane^7, groups-of-4 uniform by then),
// level4 = row_mirror (lane^15).
template <int CTRL>
static __device__ __forceinline__ float dmax(float v) {
  return fmaxf(v, __builtin_bit_cast(float, __builtin_amdgcn_update_dpp(
      0, __builtin_bit_cast(int, v), CTRL, 0xF, 0xF, true)));
}
template <int CTRL>
static __device__ __forceinline__ float dsum(float v) {
  return v + __builtin_bit_cast(float, __builtin_amdgcn_update_dpp(
      0, __builtin_bit_cast(int, v), CTRL, 0xF, 0xF, true));
}
static __device__ __forceinline__ float red16_max(float v) {
  return dmax<0x140>(dmax<0x141>(dmax<0x4E>(dmax<0xB1>(v))));
}
static __device__ __forceinline__ float red16_sum(float v) {
  return dsum<0x140>(dsum<0x141>(dsum<0x4E>(dsum<0xB1>(v))));
}

// ---------------- GroupNorm -> t bf16 [b][s][c] ----------------
__global__ __launch_bounds__(256) void gn_kernel(const float* __restrict__ x,
    const float* __restrict__ gamma, const float* __restrict__ beta,
    unsigned short* __restrict__ t) {
  int bg = blockIdx.x;
  int b = bg >> 5, g = bg & 31;
  const float* xp = x + ((size_t)(b * C_ + g * CPG_)) * HW_;
  float s = 0.f, ss = 0.f;
  for (int i = threadIdx.x; i < CPG_ * HW_; i += 256) {
    float v = xp[i]; s += v; ss += v * v;
  }
#pragma unroll
  for (int m = 32; m; m >>= 1) { s += __shfl_xor(s, m); ss += __shfl_xor(ss, m); }
  __shared__ float red[8];
  if ((threadIdx.x & 63) == 0) { red[threadIdx.x >> 6] = s; red[4 + (threadIdx.x >> 6)] = ss; }
  __syncthreads();
  float S = red[0] + red[1] + red[2] + red[3];
  float SS = red[4] + red[5] + red[6] + red[7];
  float mean = S * (1.f / 32768.f);
  float var = SS * (1.f / 32768.f) - mean * mean;
  float rs = rsqrtf(var + 1e-6f);
  float gam[CPG_], bet[CPG_];
#pragma unroll
  for (int cc = 0; cc < CPG_; ++cc) {
    float gm = gamma[g * CPG_ + cc];
    gam[cc] = gm * rs;
    bet[cc] = beta[g * CPG_ + cc] - mean * gm * rs;
  }
  for (int sp = threadIdx.x; sp < HW_; sp += 256) {
    u16x8 o;
#pragma unroll
    for (int cc = 0; cc < CPG_; ++cc) {
      float v = xp[cc * HW_ + sp];
      o[cc] = f2bf(v * gam[cc] + bet[cc]);
    }
    *(u16x8*)(t + ((size_t)(b * HW_ + sp)) * C_ + g * CPG_) = o;
  }
}

// ---------------- u = sigmoid(t . wu + bu), one wave per token ----------------
__global__ __launch_bounds__(256) void u_kernel(const unsigned short* __restrict__ t,
    const float* __restrict__ wu, const float* __restrict__ bu,
    float* __restrict__ uout) {
  int w = threadIdx.x >> 6, l = threadIdx.x & 63;
  int tok = blockIdx.x * 4 + w;
  u16x4 tv = *(const u16x4*)(t + (size_t)tok * C_ + l * 4);
  f32x4 wv4 = *(const f32x4*)(wu + l * 4);
  float d = bf2f(tv[0]) * wv4[0] + bf2f(tv[1]) * wv4[1] +
            bf2f(tv[2]) * wv4[2] + bf2f(tv[3]) * wv4[3];
#pragma unroll
  for (int m = 32; m; m >>= 1) d += __shfl_xor(d, m);
  if (l == 0) uout[tok] = 1.f / (1.f + __expf(-(d + bu[0])));
}

// ---------------- fused QKV projection GEMM (W staged in LDS as bf16) ----------------
__global__ __launch_bounds__(256, 2) void qkv_kernel(const unsigned short* __restrict__ t,
    const float* __restrict__ wq, const float* __restrict__ wk, const float* __restrict__ wv,
    const float* __restrict__ bq, const float* __restrict__ bk, const float* __restrict__ bv,
    unsigned short* __restrict__ q, unsigned short* __restrict__ k,
    unsigned short* __restrict__ vt) {
  int mblk = blockIdx.x, nblk = blockIdx.y;
  int wsel = nblk >> 2;
  int n0 = (nblk & 3) * 64;
  const float* W = wsel == 0 ? wq : (wsel == 1 ? wk : wv);
  const float* bias = wsel == 0 ? bq : (wsel == 1 ? bk : bv);
  __shared__ unsigned short WL[64][264];   // 64 out-cols x 256 k, +8 pad
  int tid = threadIdx.x;
#pragma unroll
  for (int p = 0; p < 8; ++p) {
    int row = p * 8 + (tid >> 5);
    int kc0 = (tid & 31) * 8;
    *(bf16x8*)&WL[row][kc0] = cvt8(W + (size_t)(n0 + row) * C_ + kc0);
  }
  __syncthreads();
  int wid = tid >> 6, l = tid & 63;
  int lr = l & 15, lg = l >> 4;
  int row = mblk * 64 + wid * 16 + lr;
  f32x4 acc[4] = {};
  const unsigned short* ap = t + (size_t)row * C_ + lg * 8;
#pragma unroll
  for (int kc = 0; kc < 8; ++kc) {
    bf16x8 a = ldbf8(ap + kc * 32);
#pragma unroll
    for (int j = 0; j < 4; ++j) {
      bf16x8 bb = ldbf8(&WL[j * 16 + lr][kc * 32 + lg * 8]);
      acc[j] = __builtin_amdgcn_mfma_f32_16x16x32_bf16(a, bb, acc[j], 0, 0, 0);
    }
  }
  if (wsel < 2) {
    unsigned short* dst = wsel ? k : q;
#pragma unroll
    for (int j = 0; j < 4; ++j) {
      int col = n0 + j * 16 + lr;
      float bv_ = bias[col];
#pragma unroll
      for (int r = 0; r < 4; ++r)
        dst[(size_t)(mblk * 64 + wid * 16 + lg * 4 + r) * C_ + col] = f2bf(acc[j][r] + bv_);
    }
  } else {
    __shared__ float lds[64][65];
#pragma unroll
    for (int j = 0; j < 4; ++j) {
      float bv_ = bias[n0 + j * 16 + lr];
#pragma unroll
      for (int r = 0; r < 4; ++r)
        lds[wid * 16 + lg * 4 + r][j * 16 + lr] = acc[j][r] + bv_;
    }
    __syncthreads();
    int bb_ = (mblk * 64) >> 12;
    int s0 = (mblk * 64) & 4095;
    int ss = tid & 63, cc0 = tid >> 6;
    for (int cc = cc0; cc < 64; cc += 4)
      vt[((size_t)(bb_ * C_ + n0 + cc)) * HW_ + s0 + ss] = f2bf(lds[ss][cc]);
  }
}

// ---------------- flash attention v4 ----------------
// v3 + (a) DPP butterfly softmax reductions (VALU pipe, no ds_swizzle),
// (b) defer-max rescale skip, (c) V tile bank-swizzle (col ^= (row&3)<<4,
// both sides), (d) P tile padded to [16][40] for conflict-free b128 reads.
__global__ __launch_bounds__(512, 2) void flash_kernel(const unsigned short* __restrict__ q,
    const unsigned short* __restrict__ k, const unsigned short* __restrict__ vt,
    const float* __restrict__ u, unsigned short* __restrict__ o) {
  extern __shared__ char smem[];
  // Ks [2 buf][2 half][32*256 bf16]  @ 0      (65536)
  // Vs [2 buf][2 half][256*32 bf16]  @ 65536  (65536, swizzled)
  // Pl [8 wave][16][40] bf16         @ 131072 (10240)
  // cmb_m [8][16] f32 @ 141312 ; cmb_l @ 141824 ; Lx[64] @ 142336
  // epilogue overlay: Oacc [64][260] f32 @ 0
  unsigned short* Pl = (unsigned short*)(smem + 131072);
  float* cmb_m = (float*)(smem + 141312);
  float* cmb_l = (float*)(smem + 141824);
  float* Lx    = (float*)(smem + 142336);
  float* Oacc  = (float*)smem;

  int blk = blockIdx.x;
  int b = blk >> 6;
  int qrow0 = (blk & 63) * 64;
  int tid = threadIdx.x;
  int wid = tid >> 6, l = tid & 63;
  int lr = l & 15, lg = l >> 4;
  int half = wid >> 2, qw = wid & 3;
  unsigned short* Pw = Pl + wid * 640;     // [16][40]

  const unsigned short* kb = k + (size_t)b * HW_ * C_;
  const unsigned short* vb = vt + (size_t)b * C_ * HW_;
  const float* ub = u + b * HW_;

  bf16x8 qf[8];
  const unsigned short* qp = q + ((size_t)b * HW_ + qrow0 + qw * 16 + lr) * C_ + lg * 8;
#pragma unroll
  for (int kc = 0; kc < 8; ++kc) qf[kc] = ldbf8(qp + kc * 32);

  f32x4 oa[16];
#pragma unroll
  for (int nt = 0; nt < 16; ++nt) oa[nt] = (f32x4){0.f, 0.f, 0.f, 0.f};
  float mrow[4] = {-1e30f, -1e30f, -1e30f, -1e30f};
  float lrow[4] = {0.f, 0.f, 0.f, 0.f};

  // staging role: waves 0-3 stage K, 4-7 stage V; sh = half staged
  int sh = (wid >> 1) & 1;
  int tb = (wid & 1) * 8;

#define STAGE(IT, BUFN)                                                            \
  {                                                                                \
    int key0n = sh * 2048 + (IT) * 32;                                             \
    if (wid < 4) {                                                                 \
      _Pragma("unroll")                                                            \
      for (int j = 0; j < 8; ++j) {                                                \
        int t16 = tb + j;                                                          \
        int row = t16 * 2 + (l >> 5);                                              \
        int cb = (l & 31) * 16;                                                    \
        const unsigned short* g =                                                  \
            kb + (size_t)(key0n + row) * C_ + ((cb ^ ((row & 7) << 4)) >> 1);      \
        gload16(g, smem + (BUFN) * 32768 + sh * 16384 + t16 * 1024);               \
      }                                                                            \
    } else {                                                                       \
      _Pragma("unroll")                                                            \
      for (int j = 0; j < 8; ++j) {                                                \
        int t16 = tb + j;                                                          \
        int ch = t16 * 16 + (l >> 2);                                              \
        int sc_ = ((l & 3) * 8) ^ (((l >> 2) & 3) << 3);                           \
        const unsigned short* g = vb + (size_t)ch * HW_ + key0n + sc_;             \
        gload16(g, smem + 65536 + (BUFN) * 32768 + sh * 16384 + t16 * 1024);       \
      }                                                                            \
    }                                                                              \
  }

  STAGE(0, 0);
  __syncthreads();

  for (int it = 0; it < 64; ++it) {
    int buf = it & 1;
    if (it + 1 < 64) STAGE(it + 1, buf ^ 1);
    int key0 = half * 2048 + it * 32;
    float f0 = SCALE * ub[key0 + lr];
    float f1 = SCALE * ub[key0 + 16 + lr];
    const char* KB = smem + buf * 32768 + half * 16384;
    f32x4 s0 = {0.f, 0.f, 0.f, 0.f}, s1 = {0.f, 0.f, 0.f, 0.f};
#pragma unroll
    for (int kc = 0; kc < 8; ++kc) {
      int c = lg * 16 + kc * 64;
      int cs = c ^ ((lr & 7) << 4);
      bf16x8 k0 = ldbf8((const unsigned short*)(KB + lr * 512 + cs));
      bf16x8 k1 = ldbf8((const unsigned short*)(KB + (lr + 16) * 512 + cs));
      s0 = __builtin_amdgcn_mfma_f32_16x16x32_bf16(qf[kc], k0, s0, 0, 0, 0);
      s1 = __builtin_amdgcn_mfma_f32_16x16x32_bf16(qf[kc], k1, s1, 0, 0, 0);
    }
    float mx[4];
#pragma unroll
    for (int r = 0; r < 4; ++r) {
      s0[r] *= f0; s1[r] *= f1;
      mx[r] = red16_max(fmaxf(s0[r], s1[r]));
    }
    bool need = !__all(mx[0] <= mrow[0] && mx[1] <= mrow[1] &&
                       mx[2] <= mrow[2] && mx[3] <= mrow[3]);
    if (need) {
      float scr[4];
#pragma unroll
      for (int r = 0; r < 4; ++r) {
        float mnew = fmaxf(mrow[r], mx[r]);
        scr[r] = __expf(mrow[r] - mnew);
        mrow[r] = mnew;
        lrow[r] *= scr[r];
      }
#pragma unroll
      for (int nt = 0; nt < 16; ++nt) {
        oa[nt][0] *= scr[0]; oa[nt][1] *= scr[1];
        oa[nt][2] *= scr[2]; oa[nt][3] *= scr[3];
      }
    }
#pragma unroll
    for (int r = 0; r < 4; ++r) {
      float e0 = __expf(s0[r] - mrow[r]);
      float e1 = __expf(s1[r] - mrow[r]);
      lrow[r] += red16_sum(e0 + e1);
      Pw[(lg * 4 + r) * 40 + lr] = f2bf(e0);
      Pw[(lg * 4 + r) * 40 + lr + 16] = f2bf(e1);
    }
    bf16x8 pa = ldbf8(Pw + lr * 40 + lg * 8);
    const char* VB = smem + 65536 + buf * 32768 + half * 16384;
#pragma unroll
    for (int nt = 0; nt < 16; ++nt) {
      bf16x8 vf = ldbf8((const unsigned short*)(VB + (nt * 16 + lr) * 64 +
                                                ((lg * 16) ^ ((lr & 3) << 4))));
      oa[nt] = __builtin_amdgcn_mfma_f32_16x16x32_bf16(pa, vf, oa[nt], 0, 0, 0);
    }
    __syncthreads();
  }

  // ---- pairwise combine (wave qw <-> wave qw+4) ----
#pragma unroll
  for (int r = 0; r < 4; ++r)
    if (lr == 0) { cmb_m[wid * 16 + lg * 4 + r] = mrow[r]; cmb_l[wid * 16 + lg * 4 + r] = lrow[r]; }
  __syncthreads();
  float scl[4];
#pragma unroll
  for (int r = 0; r < 4; ++r) {
    float mo = cmb_m[(wid ^ 4) * 16 + lg * 4 + r];
    float M = fmaxf(mrow[r], mo);
    scl[r] = __expf(mrow[r] - M);
  }
  if (half == 0) {
#pragma unroll
    for (int nt = 0; nt < 16; ++nt)
#pragma unroll
      for (int r = 0; r < 4; ++r)
        Oacc[(qw * 16 + lg * 4 + r) * 260 + nt * 16 + lr] = oa[nt][r] * scl[r];
  }
  if (tid < 64) {
    float m0 = cmb_m[(tid >> 4) * 16 + (tid & 15)];
    float m1 = cmb_m[((tid >> 4) + 4) * 16 + (tid & 15)];
    float l0 = cmb_l[(tid >> 4) * 16 + (tid & 15)];
    float l1 = cmb_l[((tid >> 4) + 4) * 16 + (tid & 15)];
    float M = fmaxf(m0, m1);
    Lx[tid] = l0 * __expf(m0 - M) + l1 * __expf(m1 - M);
  }
  __syncthreads();
  if (half == 1) {
#pragma unroll
    for (int nt = 0; nt < 16; ++nt)
#pragma unroll
      for (int r = 0; r < 4; ++r)
        Oacc[(qw * 16 + lg * 4 + r) * 260 + nt * 16 + lr] += oa[nt][r] * scl[r];
  }
  __syncthreads();
  for (int e = tid; e < 64 * 256; e += 512) {
    int row = e >> 8, col = e & 255;
    o[((size_t)b * HW_ + qrow0 + row) * C_ + col] =
        f2bf(Oacc[row * 260 + col] * (1.f / Lx[row]));
  }
#undef STAGE
}

// ---------------- out-proj + bias + residual (W staged in LDS as bf16) ----------------
__global__ __launch_bounds__(256, 2) void proj_kernel(const unsigned short* __restrict__ o,
    const float* __restrict__ wp, const float* __restrict__ bp,
    const float* __restrict__ x, float* __restrict__ y) {
  int mblk = blockIdx.x, nblk = blockIdx.y;
  int n0 = nblk * 64;
  __shared__ unsigned short WL[64][264];
  int tid = threadIdx.x;
#pragma unroll
  for (int p = 0; p < 8; ++p) {
    int row = p * 8 + (tid >> 5);
    int kc0 = (tid & 31) * 8;
    *(bf16x8*)&WL[row][kc0] = cvt8(wp + (size_t)(n0 + row) * C_ + kc0);
  }
  __syncthreads();
  int wid = tid >> 6, l = tid & 63;
  int lr = l & 15, lg = l >> 4;
  int row = mblk * 64 + wid * 16 + lr;
  f32x4 acc[4] = {};
  const unsigned short* ap = o + (size_t)row * C_ + lg * 8;
#pragma unroll
  for (int kc = 0; kc < 8; ++kc) {
    bf16x8 a = ldbf8(ap + kc * 32);
#pragma unroll
    for (int j = 0; j < 4; ++j) {
      bf16x8 bb = ldbf8(&WL[j * 16 + lr][kc * 32 + lg * 8]);
      acc[j] = __builtin_amdgcn_mfma_f32_16x16x32_bf16(a, bb, acc[j], 0, 0, 0);
    }
  }
  __shared__ float lds[64][65];
#pragma unroll
  for (int j = 0; j < 4; ++j) {
    float bv_ = bp[n0 + j * 16 + lr];
#pragma unroll
    for (int r = 0; r < 4; ++r)
      lds[wid * 16 + lg * 4 + r][j * 16 + lr] = acc[j][r] + bv_;
  }
  __syncthreads();
  int bb_ = (mblk * 64) >> 12;
  int s0 = (mblk * 64) & 4095;
  int ss = tid & 63, cc0 = tid >> 6;
  for (int cc = cc0; cc < 64; cc += 4) {
    size_t idx = ((size_t)(bb_ * C_ + n0 + cc)) * HW_ + s0 + ss;
    y[idx] = x[idx] + lds[ss][cc];
  }
}

extern "C" void kernel_launch(void* const* d_in, const int* in_sizes, int n_in,
                              void* d_out, int out_size, void* d_ws, size_t ws_size,
                              hipStream_t stream) {
  const float* x     = (const float*)d_in[0];
  const float* gamma = (const float*)d_in[1];
  const float* beta  = (const float*)d_in[2];
  const float* wq    = (const float*)d_in[3];
  const float* bq    = (const float*)d_in[4];
  const float* wk    = (const float*)d_in[5];
  const float* bk    = (const float*)d_in[6];
  const float* wv    = (const float*)d_in[7];
  const float* bv    = (const float*)d_in[8];
  const float* wu    = (const float*)d_in[9];
  const float* bu    = (const float*)d_in[10];
  const float* wp    = (const float*)d_in[11];
  const float* bp    = (const float*)d_in[12];

  float* y = (float*)d_out;
  float* uout = y + (size_t)B_ * C_ * HW_;  // output 1 region, also read by flash

  unsigned short* t  = (unsigned short*)d_ws;        // 8 MB, reused as attn output O
  unsigned short* q  = t + (size_t)M_TOT * C_;       // 8 MB
  unsigned short* kk = q + (size_t)M_TOT * C_;       // 8 MB
  unsigned short* vt = kk + (size_t)M_TOT * C_;      // 8 MB, [b][c][s]

  hipFuncSetAttribute((const void*)flash_kernel,
                      hipFuncAttributeMaxDynamicSharedMemorySize, FLASH_LDS);

  gn_kernel<<<128, 256, 0, stream>>>(x, gamma, beta, t);
  u_kernel<<<4096, 256, 0, stream>>>(t, wu, bu, uout);
  qkv_kernel<<<dim3(256, 12), 256, 0, stream>>>(t, wq, wk, wv, bq, bk, bv, q, kk, vt);
  flash_kernel<<<256, 512, FLASH_LDS, stream>>>(q, kk, vt, uout, t);
  proj_kernel<<<dim3(256, 4), 256, 0, stream>>>(t, wp, bp, x, y);
}

// Round 5
// 228.276 us; speedup vs baseline: 5.0296x; 1.0587x over previous
//
#include <hip/hip_runtime.h>
#include <cstdint>

#define B_ 4
#define C_ 256
#define HW_ 4096
#define CPG_ 8
#define M_TOT 16384
#define SCALE 0.0625f
#define FLASH_LDS 142592

typedef __attribute__((ext_vector_type(4))) float f32x4;
typedef __attribute__((ext_vector_type(8))) unsigned short u16x8;
typedef __attribute__((ext_vector_type(4))) unsigned short u16x4;
typedef __attribute__((ext_vector_type(8))) __bf16 bf16x8;

static __device__ __forceinline__ unsigned short f2bf(float f) {
  unsigned int u = __builtin_bit_cast(unsigned int, f);
  u += 0x7fffu + ((u >> 16) & 1u);
  return (unsigned short)(u >> 16);
}
static __device__ __forceinline__ float bf2f(unsigned short s) {
  return __builtin_bit_cast(float, ((unsigned int)s) << 16);
}
static __device__ __forceinline__ bf16x8 ldbf8(const unsigned short* p) {
  return __builtin_bit_cast(bf16x8, *(const u16x8*)p);
}
static __device__ __forceinline__ bf16x8 cvt8(const float* p) {
  f32x4 a = *(const f32x4*)p;
  f32x4 b = *(const f32x4*)(p + 4);
  u16x8 r;
  r[0] = f2bf(a[0]); r[1] = f2bf(a[1]); r[2] = f2bf(a[2]); r[3] = f2bf(a[3]);
  r[4] = f2bf(b[0]); r[5] = f2bf(b[1]); r[6] = f2bf(b[2]); r[7] = f2bf(b[3]);
  return __builtin_bit_cast(bf16x8, r);
}
// async global->LDS, 16B per lane; LDS dest must be wave-uniform base
static __device__ __forceinline__ void gload16(const void* g, void* l) {
  __builtin_amdgcn_global_load_lds(
      (const __attribute__((address_space(1))) unsigned int*)g,
      (__attribute__((address_space(3))) unsigned int*)l, 16, 0, 0);
}
// DPP butterfly steps within 16-lane groups (VALU pipe, not LDS)
template <int CTRL>
static __device__ __forceinline__ float dmax(float v) {
  return fmaxf(v, __builtin_bit_cast(float, __builtin_amdgcn_update_dpp(
      0, __builtin_bit_cast(int, v), CTRL, 0xF, 0xF, true)));
}
template <int CTRL>
static __device__ __forceinline__ float dsum(float v) {
  return v + __builtin_bit_cast(float, __builtin_amdgcn_update_dpp(
      0, __builtin_bit_cast(int, v), CTRL, 0xF, 0xF, true));
}
static __device__ __forceinline__ float red16_max(float v) {
  return dmax<0x140>(dmax<0x141>(dmax<0x4E>(dmax<0xB1>(v))));
}
static __device__ __forceinline__ float red16_sum(float v) {
  return dsum<0x140>(dsum<0x141>(dsum<0x4E>(dsum<0xB1>(v))));
}

// ---------------- GroupNorm -> t bf16 [b][s][c] ----------------
__global__ __launch_bounds__(256) void gn_kernel(const float* __restrict__ x,
    const float* __restrict__ gamma, const float* __restrict__ beta,
    unsigned short* __restrict__ t) {
  int bg = blockIdx.x;
  int b = bg >> 5, g = bg & 31;
  const float* xp = x + ((size_t)(b * C_ + g * CPG_)) * HW_;
  float s = 0.f, ss = 0.f;
  for (int i = threadIdx.x; i < CPG_ * HW_; i += 256) {
    float v = xp[i]; s += v; ss += v * v;
  }
#pragma unroll
  for (int m = 32; m; m >>= 1) { s += __shfl_xor(s, m); ss += __shfl_xor(ss, m); }
  __shared__ float red[8];
  if ((threadIdx.x & 63) == 0) { red[threadIdx.x >> 6] = s; red[4 + (threadIdx.x >> 6)] = ss; }
  __syncthreads();
  float S = red[0] + red[1] + red[2] + red[3];
  float SS = red[4] + red[5] + red[6] + red[7];
  float mean = S * (1.f / 32768.f);
  float var = SS * (1.f / 32768.f) - mean * mean;
  float rs = rsqrtf(var + 1e-6f);
  float gam[CPG_], bet[CPG_];
#pragma unroll
  for (int cc = 0; cc < CPG_; ++cc) {
    float gm = gamma[g * CPG_ + cc];
    gam[cc] = gm * rs;
    bet[cc] = beta[g * CPG_ + cc] - mean * gm * rs;
  }
  for (int sp = threadIdx.x; sp < HW_; sp += 256) {
    u16x8 o;
#pragma unroll
    for (int cc = 0; cc < CPG_; ++cc) {
      float v = xp[cc * HW_ + sp];
      o[cc] = f2bf(v * gam[cc] + bet[cc]);
    }
    *(u16x8*)(t + ((size_t)(b * HW_ + sp)) * C_ + g * CPG_) = o;
  }
}

// ---------------- u = sigmoid(t . wu + bu), one wave per token ----------------
__global__ __launch_bounds__(256) void u_kernel(const unsigned short* __restrict__ t,
    const float* __restrict__ wu, const float* __restrict__ bu,
    float* __restrict__ uout) {
  int w = threadIdx.x >> 6, l = threadIdx.x & 63;
  int tok = blockIdx.x * 4 + w;
  u16x4 tv = *(const u16x4*)(t + (size_t)tok * C_ + l * 4);
  f32x4 wv4 = *(const f32x4*)(wu + l * 4);
  float d = bf2f(tv[0]) * wv4[0] + bf2f(tv[1]) * wv4[1] +
            bf2f(tv[2]) * wv4[2] + bf2f(tv[3]) * wv4[3];
#pragma unroll
  for (int m = 32; m; m >>= 1) d += __shfl_xor(d, m);
  if (l == 0) uout[tok] = 1.f / (1.f + __expf(-(d + bu[0])));
}

// ---------------- fused QKV projection GEMM (W staged in LDS as bf16) ----------------
__global__ __launch_bounds__(256, 2) void qkv_kernel(const unsigned short* __restrict__ t,
    const float* __restrict__ wq, const float* __restrict__ wk, const float* __restrict__ wv,
    const float* __restrict__ bq, const float* __restrict__ bk, const float* __restrict__ bv,
    unsigned short* __restrict__ q, unsigned short* __restrict__ k,
    unsigned short* __restrict__ vt) {
  int mblk = blockIdx.x, nblk = blockIdx.y;
  int wsel = nblk >> 2;
  int n0 = (nblk & 3) * 64;
  const float* W = wsel == 0 ? wq : (wsel == 1 ? wk : wv);
  const float* bias = wsel == 0 ? bq : (wsel == 1 ? bk : bv);
  __shared__ unsigned short WL[64][264];   // 64 out-cols x 256 k, +8 pad
  int tid = threadIdx.x;
#pragma unroll
  for (int p = 0; p < 8; ++p) {
    int row = p * 8 + (tid >> 5);
    int kc0 = (tid & 31) * 8;
    *(bf16x8*)&WL[row][kc0] = cvt8(W + (size_t)(n0 + row) * C_ + kc0);
  }
  __syncthreads();
  int wid = tid >> 6, l = tid & 63;
  int lr = l & 15, lg = l >> 4;
  int row = mblk * 64 + wid * 16 + lr;
  f32x4 acc[4] = {};
  const unsigned short* ap = t + (size_t)row * C_ + lg * 8;
#pragma unroll
  for (int kc = 0; kc < 8; ++kc) {
    bf16x8 a = ldbf8(ap + kc * 32);
#pragma unroll
    for (int j = 0; j < 4; ++j) {
      bf16x8 bb = ldbf8(&WL[j * 16 + lr][kc * 32 + lg * 8]);
      acc[j] = __builtin_amdgcn_mfma_f32_16x16x32_bf16(a, bb, acc[j], 0, 0, 0);
    }
  }
  if (wsel < 2) {
    unsigned short* dst = wsel ? k : q;
#pragma unroll
    for (int j = 0; j < 4; ++j) {
      int col = n0 + j * 16 + lr;
      float bv_ = bias[col];
#pragma unroll
      for (int r = 0; r < 4; ++r)
        dst[(size_t)(mblk * 64 + wid * 16 + lg * 4 + r) * C_ + col] = f2bf(acc[j][r] + bv_);
    }
  } else {
    __shared__ float lds[64][65];
#pragma unroll
    for (int j = 0; j < 4; ++j) {
      float bv_ = bias[n0 + j * 16 + lr];
#pragma unroll
      for (int r = 0; r < 4; ++r)
        lds[wid * 16 + lg * 4 + r][j * 16 + lr] = acc[j][r] + bv_;
    }
    __syncthreads();
    int bb_ = (mblk * 64) >> 12;
    int s0 = (mblk * 64) & 4095;
    int ss = tid & 63, cc0 = tid >> 6;
    for (int cc = cc0; cc < 64; cc += 4)
      vt[((size_t)(bb_ * C_ + n0 + cc)) * HW_ + s0 + ss] = f2bf(lds[ss][cc]);
  }
}

// ---------------- flash attention v5 ----------------
// v4 + (a) true defer-max THR=8 with per-lane local gate (reduce only on
// fire), (b) deferred l-sum (per-lane partials, one red16_sum at end),
// (c) corrected V bank swizzle ((lr>>1)&3 — 8-slot spread under 16-lane
// phasing), (d) s_setprio(1) around MFMA clusters.
__global__ __launch_bounds__(512, 2) void flash_kernel(const unsigned short* __restrict__ q,
    const unsigned short* __restrict__ k, const unsigned short* __restrict__ vt,
    const float* __restrict__ u, unsigned short* __restrict__ o) {
  extern __shared__ char smem[];
  // Ks [2 buf][2 half][32*256 bf16]  @ 0      (65536)
  // Vs [2 buf][2 half][256*32 bf16]  @ 65536  (65536, swizzled)
  // Pl [8 wave][16][40] bf16         @ 131072 (10240)
  // cmb_m [8][16] f32 @ 141312 ; cmb_l @ 141824 ; Lx[64] @ 142336
  // epilogue overlay: Oacc [64][260] f32 @ 0
  unsigned short* Pl = (unsigned short*)(smem + 131072);
  float* cmb_m = (float*)(smem + 141312);
  float* cmb_l = (float*)(smem + 141824);
  float* Lx    = (float*)(smem + 142336);
  float* Oacc  = (float*)smem;

  int blk = blockIdx.x;
  int b = blk >> 6;
  int qrow0 = (blk & 63) * 64;
  int tid = threadIdx.x;
  int wid = tid >> 6, l = tid & 63;
  int lr = l & 15, lg = l >> 4;
  int half = wid >> 2, qw = wid & 3;
  unsigned short* Pw = Pl + wid * 640;     // [16][40]

  const unsigned short* kb = k + (size_t)b * HW_ * C_;
  const unsigned short* vb = vt + (size_t)b * C_ * HW_;
  const float* ub = u + b * HW_;

  bf16x8 qf[8];
  const unsigned short* qp = q + ((size_t)b * HW_ + qrow0 + qw * 16 + lr) * C_ + lg * 8;
#pragma unroll
  for (int kc = 0; kc < 8; ++kc) qf[kc] = ldbf8(qp + kc * 32);

  f32x4 oa[16];
#pragma unroll
  for (int nt = 0; nt < 16; ++nt) oa[nt] = (f32x4){0.f, 0.f, 0.f, 0.f};
  float mrow[4] = {-1e30f, -1e30f, -1e30f, -1e30f};
  float lrow[4] = {0.f, 0.f, 0.f, 0.f};   // per-lane partial sums until final reduce

  // staging role: waves 0-3 stage K, 4-7 stage V; sh = half staged
  int sh = (wid >> 1) & 1;
  int tb = (wid & 1) * 8;

#define STAGE(IT, BUFN)                                                            \
  {                                                                                \
    int key0n = sh * 2048 + (IT) * 32;                                             \
    if (wid < 4) {                                                                 \
      _Pragma("unroll")                                                            \
      for (int j = 0; j < 8; ++j) {                                                \
        int t16 = tb + j;                                                          \
        int row = t16 * 2 + (l >> 5);                                              \
        int cb = (l & 31) * 16;                                                    \
        const unsigned short* g =                                                  \
            kb + (size_t)(key0n + row) * C_ + ((cb ^ ((row & 7) << 4)) >> 1);      \
        gload16(g, smem + (BUFN) * 32768 + sh * 16384 + t16 * 1024);               \
      }                                                                            \
    } else {                                                                       \
      _Pragma("unroll")                                                            \
      for (int j = 0; j < 8; ++j) {                                                \
        int t16 = tb + j;                                                          \
        int ch = t16 * 16 + (l >> 2);                                              \
        int sc_ = (((l & 3) ^ ((l >> 3) & 3)) * 8);                                \
        const unsigned short* g = vb + (size_t)ch * HW_ + key0n + sc_;             \
        gload16(g, smem + 65536 + (BUFN) * 32768 + sh * 16384 + t16 * 1024);       \
      }                                                                            \
    }                                                                              \
  }

  STAGE(0, 0);
  __syncthreads();

  for (int it = 0; it < 64; ++it) {
    int buf = it & 1;
    if (it + 1 < 64) STAGE(it + 1, buf ^ 1);
    int key0 = half * 2048 + it * 32;
    float f0 = SCALE * ub[key0 + lr];
    float f1 = SCALE * ub[key0 + 16 + lr];
    const char* KB = smem + buf * 32768 + half * 16384;
    f32x4 s0 = {0.f, 0.f, 0.f, 0.f}, s1 = {0.f, 0.f, 0.f, 0.f};
    __builtin_amdgcn_s_setprio(1);
#pragma unroll
    for (int kc = 0; kc < 8; ++kc) {
      int c = lg * 16 + kc * 64;
      int cs = c ^ ((lr & 7) << 4);
      bf16x8 k0 = ldbf8((const unsigned short*)(KB + lr * 512 + cs));
      bf16x8 k1 = ldbf8((const unsigned short*)(KB + (lr + 16) * 512 + cs));
      s0 = __builtin_amdgcn_mfma_f32_16x16x32_bf16(qf[kc], k0, s0, 0, 0, 0);
      s1 = __builtin_amdgcn_mfma_f32_16x16x32_bf16(qf[kc], k1, s1, 0, 0, 0);
    }
    __builtin_amdgcn_s_setprio(0);
    // --- softmax with true defer-max (THR=8): fast path has NO reductions ---
    float mxl[4];
#pragma unroll
    for (int r = 0; r < 4; ++r) {
      s0[r] *= f0; s1[r] *= f1;
      mxl[r] = fmaxf(s0[r], s1[r]);
    }
    bool ok = (mxl[0] <= mrow[0] + 8.f) && (mxl[1] <= mrow[1] + 8.f) &&
              (mxl[2] <= mrow[2] + 8.f) && (mxl[3] <= mrow[3] + 8.f);
    if (!__all(ok)) {
      float scr[4];
#pragma unroll
      for (int r = 0; r < 4; ++r) {
        float mx = red16_max(mxl[r]);
        float mnew = fmaxf(mrow[r], mx);
        scr[r] = __expf(mrow[r] - mnew);
        mrow[r] = mnew;
        lrow[r] *= scr[r];
      }
#pragma unroll
      for (int nt = 0; nt < 16; ++nt) {
        oa[nt][0] *= scr[0]; oa[nt][1] *= scr[1];
        oa[nt][2] *= scr[2]; oa[nt][3] *= scr[3];
      }
    }
#pragma unroll
    for (int r = 0; r < 4; ++r) {
      float e0 = __expf(s0[r] - mrow[r]);
      float e1 = __expf(s1[r] - mrow[r]);
      lrow[r] += e0 + e1;
      Pw[(lg * 4 + r) * 40 + lr] = f2bf(e0);
      Pw[(lg * 4 + r) * 40 + lr + 16] = f2bf(e1);
    }
    bf16x8 pa = ldbf8(Pw + lr * 40 + lg * 8);
    const char* VB = smem + 65536 + buf * 32768 + half * 16384;
    __builtin_amdgcn_s_setprio(1);
#pragma unroll
    for (int nt = 0; nt < 16; ++nt) {
      bf16x8 vf = ldbf8((const unsigned short*)(VB + (nt * 16 + lr) * 64 +
                                                ((lg * 16) ^ (((lr >> 1) & 3) << 4))));
      oa[nt] = __builtin_amdgcn_mfma_f32_16x16x32_bf16(pa, vf, oa[nt], 0, 0, 0);
    }
    __builtin_amdgcn_s_setprio(0);
    __syncthreads();
  }

  // finalize per-row sums (deferred reduction)
#pragma unroll
  for (int r = 0; r < 4; ++r) lrow[r] = red16_sum(lrow[r]);

  // ---- pairwise combine (wave qw <-> wave qw+4) ----
#pragma unroll
  for (int r = 0; r < 4; ++r)
    if (lr == 0) { cmb_m[wid * 16 + lg * 4 + r] = mrow[r]; cmb_l[wid * 16 + lg * 4 + r] = lrow[r]; }
  __syncthreads();
  float scl[4];
#pragma unroll
  for (int r = 0; r < 4; ++r) {
    float mo = cmb_m[(wid ^ 4) * 16 + lg * 4 + r];
    float M = fmaxf(mrow[r], mo);
    scl[r] = __expf(mrow[r] - M);
  }
  if (half == 0) {
#pragma unroll
    for (int nt = 0; nt < 16; ++nt)
#pragma unroll
      for (int r = 0; r < 4; ++r)
        Oacc[(qw * 16 + lg * 4 + r) * 260 + nt * 16 + lr] = oa[nt][r] * scl[r];
  }
  if (tid < 64) {
    float m0 = cmb_m[(tid >> 4) * 16 + (tid & 15)];
    float m1 = cmb_m[((tid >> 4) + 4) * 16 + (tid & 15)];
    float l0 = cmb_l[(tid >> 4) * 16 + (tid & 15)];
    float l1 = cmb_l[((tid >> 4) + 4) * 16 + (tid & 15)];
    float M = fmaxf(m0, m1);
    Lx[tid] = l0 * __expf(m0 - M) + l1 * __expf(m1 - M);
  }
  __syncthreads();
  if (half == 1) {
#pragma unroll
    for (int nt = 0; nt < 16; ++nt)
#pragma unroll
      for (int r = 0; r < 4; ++r)
        Oacc[(qw * 16 + lg * 4 + r) * 260 + nt * 16 + lr] += oa[nt][r] * scl[r];
  }
  __syncthreads();
  for (int e = tid; e < 64 * 256; e += 512) {
    int row = e >> 8, col = e & 255;
    o[((size_t)b * HW_ + qrow0 + row) * C_ + col] =
        f2bf(Oacc[row * 260 + col] * (1.f / Lx[row]));
  }
#undef STAGE
}

// ---------------- out-proj + bias + residual (W staged in LDS as bf16) ----------------
__global__ __launch_bounds__(256, 2) void proj_kernel(const unsigned short* __restrict__ o,
    const float* __restrict__ wp, const float* __restrict__ bp,
    const float* __restrict__ x, float* __restrict__ y) {
  int mblk = blockIdx.x, nblk = blockIdx.y;
  int n0 = nblk * 64;
  __shared__ unsigned short WL[64][264];
  int tid = threadIdx.x;
#pragma unroll
  for (int p = 0; p < 8; ++p) {
    int row = p * 8 + (tid >> 5);
    int kc0 = (tid & 31) * 8;
    *(bf16x8*)&WL[row][kc0] = cvt8(wp + (size_t)(n0 + row) * C_ + kc0);
  }
  __syncthreads();
  int wid = tid >> 6, l = tid & 63;
  int lr = l & 15, lg = l >> 4;
  int row = mblk * 64 + wid * 16 + lr;
  f32x4 acc[4] = {};
  const unsigned short* ap = o + (size_t)row * C_ + lg * 8;
#pragma unroll
  for (int kc = 0; kc < 8; ++kc) {
    bf16x8 a = ldbf8(ap + kc * 32);
#pragma unroll
    for (int j = 0; j < 4; ++j) {
      bf16x8 bb = ldbf8(&WL[j * 16 + lr][kc * 32 + lg * 8]);
      acc[j] = __builtin_amdgcn_mfma_f32_16x16x32_bf16(a, bb, acc[j], 0, 0, 0);
    }
  }
  __shared__ float lds[64][65];
#pragma unroll
  for (int j = 0; j < 4; ++j) {
    float bv_ = bp[n0 + j * 16 + lr];
#pragma unroll
    for (int r = 0; r < 4; ++r)
      lds[wid * 16 + lg * 4 + r][j * 16 + lr] = acc[j][r] + bv_;
  }
  __syncthreads();
  int bb_ = (mblk * 64) >> 12;
  int s0 = (mblk * 64) & 4095;
  int ss = tid & 63, cc0 = tid >> 6;
  for (int cc = cc0; cc < 64; cc += 4) {
    size_t idx = ((size_t)(bb_ * C_ + n0 + cc)) * HW_ + s0 + ss;
    y[idx] = x[idx] + lds[ss][cc];
  }
}

extern "C" void kernel_launch(void* const* d_in, const int* in_sizes, int n_in,
                              void* d_out, int out_size, void* d_ws, size_t ws_size,
                              hipStream_t stream) {
  const float* x     = (const float*)d_in[0];
  const float* gamma = (const float*)d_in[1];
  const float* beta  = (const float*)d_in[2];
  const float* wq    = (const float*)d_in[3];
  const float* bq    = (const float*)d_in[4];
  const float* wk    = (const float*)d_in[5];
  const float* bk    = (const float*)d_in[6];
  const float* wv    = (const float*)d_in[7];
  const float* bv    = (const float*)d_in[8];
  const float* wu    = (const float*)d_in[9];
  const float* bu    = (const float*)d_in[10];
  const float* wp    = (const float*)d_in[11];
  const float* bp    = (const float*)d_in[12];

  float* y = (float*)d_out;
  float* uout = y + (size_t)B_ * C_ * HW_;  // output 1 region, also read by flash

  unsigned short* t  = (unsigned short*)d_ws;        // 8 MB, reused as attn output O
  unsigned short* q  = t + (size_t)M_TOT * C_;       // 8 MB
  unsigned short* kk = q + (size_t)M_TOT * C_;       // 8 MB
  unsigned short* vt = kk + (size_t)M_TOT * C_;      // 8 MB, [b][c][s]

  hipFuncSetAttribute((const void*)flash_kernel,
                      hipFuncAttributeMaxDynamicSharedMemorySize, FLASH_LDS);

  gn_kernel<<<128, 256, 0, stream>>>(x, gamma, beta, t);
  u_kernel<<<4096, 256, 0, stream>>>(t, wu, bu, uout);
  qkv_kernel<<<dim3(256, 12), 256, 0, stream>>>(t, wq, wk, wv, bq, bk, bv, q, kk, vt);
  flash_kernel<<<256, 512, FLASH_LDS, stream>>>(q, kk, vt, uout, t);
  proj_kernel<<<dim3(256, 4), 256, 0, stream>>>(t, wp, bp, x, y);
}